// Round 13
// baseline (108.962 us; speedup 1.0000x reference)
//
#include <hip/hip_runtime.h>
#include <stdint.h>

#define NPTS   4096
#define NSKIP  16384
#define CCH    256
#define CSK    128
#define DIN    384
#define HDIM   256
#define BIGF   1e10f

typedef unsigned short u16;
typedef __attribute__((ext_vector_type(8))) short short8;
typedef __attribute__((ext_vector_type(4))) float floatx4;

__device__ __forceinline__ u16 f2bf(float f) {
    union { float f; uint32_t u; } c; c.f = f;
    uint32_t u = c.u;
    return (u16)((u + 0x7FFFu + ((u >> 16) & 1u)) >> 16);
}

// Pack (non-negative fp32 dist, idx) into a positive double whose numeric
// order == (dist, idx) lexicographic order (exact top_k tie semantics).
__device__ __forceinline__ double pkkey(float d, int j) {
    return __hiloint2double(__float_as_int(d), j);
}

// ---------------------------------------------------------------------------
// k1 (R19): prep — 80 blocks. Blocks 0-47 pack W1, 48-79 pack W2 (ntile-major
// MFMA B-layout); blocks 48-63 also build pos4; block 0 builds the batch
// range table (removes the per-block binary-search chain from mega).
// ---------------------------------------------------------------------------
__global__ __launch_bounds__(256) void prep_kernel(
    const float* __restrict__ W1, const float* __restrict__ W2,
    u16* __restrict__ W1p, u16* __restrict__ W2p,
    const float* __restrict__ pos, float4* __restrict__ pos4,
    const int* __restrict__ batch, int* __restrict__ range)
{
    const int bid = blockIdx.x;
    const int t = threadIdx.x;

    const float* W = (bid < 48) ? W1 : W2;
    u16* Wp       = (bid < 48) ? W1p : W2p;
    const int KT  = (bid < 48) ? 12 : 8;
    const int g   = ((bid < 48) ? bid : (bid - 48)) * 256 + t;

    const int lane = g & 63;
    const int kt = (g >> 6) % KT;
    const int nt = (g >> 6) / KT;
    const int kbase = kt * 32 + (lane >> 4) * 8;
    const int n = nt * 16 + (lane & 15);
    u16 v[8];
#pragma unroll
    for (int j = 0; j < 8; ++j) v[j] = f2bf(W[(size_t)(kbase + j) * HDIM + n]);
#pragma unroll
    for (int j = 0; j < 8; ++j) Wp[(size_t)g * 8 + j] = v[j];

    if (bid >= 48 && bid < 64) {
        const int p = (bid - 48) * 256 + t;
        pos4[p] = make_float4(pos[p * 3 + 0], pos[p * 3 + 1], pos[p * 3 + 2], 0.0f);
    }

    if (bid == 0) {
        for (int j = t * 16; j < t * 16 + 16; ++j) {
            if (j == 0) {
                const int b0 = batch[0];
                for (int b = 0; b <= b0; ++b) range[b] = 0;
            } else {
                const int bp = batch[j - 1], bj = batch[j];
                for (int b = bp + 1; b <= bj; ++b) range[b] = j;
            }
            if (j == NPTS - 1) {
                const int bl = batch[NPTS - 1];
                for (int b = bl + 1; b <= 4; ++b) range[b] = NPTS;
            }
        }
    }
}

// ---------------------------------------------------------------------------
// k2 (R19): mega — 32 rows/block, 512 blocks (= exactly co-residency
// capacity, single dispatch wave), 1024 threads (16 waves), VGPR<=64.
// Per-wave pipeline (2 rows/wave, no block sync until sA complete):
//   skip-copy (own rows) -> KNN (32 thr/pt; butterfly leaves result in all
//   lanes) -> gather+interp (own rows, wave-private) -> bar ->
//   GEMM1 -> bar -> h pack -> bar -> GEMM2 -> epilogue -> bar -> store+tail.
// 4 barriers (was 6); range table read from ws (2 loads, was 24-load chain).
// ---------------------------------------------------------------------------
__global__ __launch_bounds__(1024, 8) void mega_kernel(
    const float* __restrict__ x, const float* __restrict__ x_skip,
    const float4* __restrict__ pos4, const int* __restrict__ range,
    const u16* __restrict__ W1p, const float* __restrict__ b1,
    const u16* __restrict__ W2p, const float* __restrict__ b2,
    const float* __restrict__ pos_skip, const int* __restrict__ batch_skip,
    float* __restrict__ out)
{
    __shared__ u16 sA[32 * 392];     // 25088 B; reused as h[32][264]
    __shared__ float sOut[32 * 256]; // 32768 B f32 epilogue staging
    const int t = threadIdx.x;
    const int row0 = blockIdx.x * 32;
    const int wave = t >> 6, lane = t & 63;
    const int quad = lane >> 4, ml = lane & 15;
    const int rl = t >> 5;           // local row 0..31 (2 per wave)
    const int sub = t & 31;          // 32 threads per row
    const int i = row0 + rl;         // global fine-point row

    // --- skip-copy for own row (independent; loads issue first) ---
    const float4 vs = *(const float4*)(x_skip + (size_t)i * CSK + sub * 4);
    // --- range lookup (2 L2 loads; precomputed in prep) ---
    const int b = batch_skip[i];
    const int start = range[b], end = range[b + 1];
    const float px = pos_skip[i * 3 + 0];
    const float py = pos_skip[i * 3 + 1];
    const float pz = pos_skip[i * 3 + 2];
    {
        uint2 pk;
        pk.x = (uint32_t)f2bf(vs.x) | ((uint32_t)f2bf(vs.y) << 16);
        pk.y = (uint32_t)f2bf(vs.z) | ((uint32_t)f2bf(vs.w) << 16);
        *(uint2*)(sA + rl * 392 + CCH + sub * 4) = pk;
    }

    // --- KNN: stride-32 scan, f64-key top-3 bubble ---
    const double BIGKEY = pkkey(BIGF, 0x7FFFFFFF);
    double k0 = BIGKEY, k1 = BIGKEY, k2 = BIGKEY;
    for (int j = start + sub; j < end; j += 32) {
        const float4 q = pos4[j];
        const float dx = __fsub_rn(px, q.x);
        const float dy = __fsub_rn(py, q.y);
        const float dz = __fsub_rn(pz, q.z);
        const float dd = __fadd_rn(__fadd_rn(__fmul_rn(dx, dx), __fmul_rn(dy, dy)),
                                   __fmul_rn(dz, dz));
        const double kk = pkkey(dd, j);
        const double u0 = fmax(k0, kk); k0 = fmin(k0, kk);
        const double u1 = fmax(k1, u0); k1 = fmin(k1, u0);
        k2 = fmin(k2, u1);
    }
    // butterfly within each 32-lane half (masks < 32 stay in-half);
    // result lands in ALL lanes of the half.
#pragma unroll
    for (int m = 1; m < 32; m <<= 1) {
        const double o0 = __shfl_xor(k0, m);
        const double o1 = __shfl_xor(k1, m);
        const double o2 = __shfl_xor(k2, m);
        double u0 = fmax(k0, o0); k0 = fmin(k0, o0);
        double u1 = fmax(k1, u0); k1 = fmin(k1, u0);
        k2 = fmin(k2, u1);
        u1 = fmax(k1, o1); k1 = fmin(k1, o1);
        k2 = fmin(k2, u1);
        k2 = fmin(k2, o2);
    }

    // --- per-lane weights (redundant across the 32-lane half; cheap) ---
    const int i0 = __double2loint(k0);
    const int i1 = __double2loint(k1);
    const int i2 = __double2loint(k2);
    {
        const float d0 = __int_as_float(__double2hiint(k0));
        const float d1 = __int_as_float(__double2hiint(k1));
        const float d2 = __int_as_float(__double2hiint(k2));
        const float w0r = 1.0f / fmaxf(d0, 1e-16f);
        const float w1r = 1.0f / fmaxf(d1, 1e-16f);
        const float w2r = 1.0f / fmaxf(d2, 1e-16f);
        const float inv = 1.0f / (w0r + w1r + w2r);
        const float w0 = w0r * inv, w1 = w1r * inv, w2 = w2r * inv;

        // --- gather + interp for own row: 8 cols per lane (32 x 8 = 256) ---
        const float* xr0 = x + (size_t)i0 * CCH + sub * 8;
        const float* xr1 = x + (size_t)i1 * CCH + sub * 8;
        const float* xr2 = x + (size_t)i2 * CCH + sub * 8;
        const float4 a0 = *(const float4*)(xr0);
        const float4 a1 = *(const float4*)(xr0 + 4);
        const float4 c0 = *(const float4*)(xr1);
        const float4 c1 = *(const float4*)(xr1 + 4);
        const float4 e0 = *(const float4*)(xr2);
        const float4 e1 = *(const float4*)(xr2 + 4);

        const float y0 = w0 * a0.x + w1 * c0.x + w2 * e0.x;
        const float y1 = w0 * a0.y + w1 * c0.y + w2 * e0.y;
        const float y2 = w0 * a0.z + w1 * c0.z + w2 * e0.z;
        const float y3 = w0 * a0.w + w1 * c0.w + w2 * e0.w;
        const float y4 = w0 * a1.x + w1 * c1.x + w2 * e1.x;
        const float y5 = w0 * a1.y + w1 * c1.y + w2 * e1.y;
        const float y6 = w0 * a1.z + w1 * c1.z + w2 * e1.z;
        const float y7 = w0 * a1.w + w1 * c1.w + w2 * e1.w;
        uint4 pk;
        pk.x = (uint32_t)f2bf(y0) | ((uint32_t)f2bf(y1) << 16);
        pk.y = (uint32_t)f2bf(y2) | ((uint32_t)f2bf(y3) << 16);
        pk.z = (uint32_t)f2bf(y4) | ((uint32_t)f2bf(y5) << 16);
        pk.w = (uint32_t)f2bf(y6) | ((uint32_t)f2bf(y7) << 16);
        *(uint4*)(sA + rl * 392 + sub * 8) = pk;
    }
    __syncthreads();

    // --- GEMM1: A[32x384] @ W1 -> h[32x256]; 1 ntile/wave ---
    floatx4 acc[2] = {};
    {
        const u16* aA = sA + ml * 392 + quad * 8;
        for (int kt = 0; kt < 12; ++kt) {
            short8 a0 = *(const short8*)(aA + kt * 32);
            short8 a1 = *(const short8*)(aA + 16 * 392 + kt * 32);
            short8 bfr = *(const short8*)(W1p + (size_t)((wave * 12 + kt) * 64 + lane) * 8);
            acc[0] = __builtin_amdgcn_mfma_f32_16x16x32_bf16(a0, bfr, acc[0], 0, 0, 0);
            acc[1] = __builtin_amdgcn_mfma_f32_16x16x32_bf16(a1, bfr, acc[1], 0, 0, 0);
        }
    }
    __syncthreads();

    // --- h = relu(acc + b1) -> LDS bf16 [32 x 264] ---
    {
        const int n = wave * 16 + ml;
        const float bv = b1[n];
#pragma unroll
        for (int mt = 0; mt < 2; ++mt) {
#pragma unroll
            for (int r = 0; r < 4; ++r) {
                const int m = mt * 16 + quad * 4 + r;
                sA[m * 264 + n] = f2bf(fmaxf(acc[mt][r] + bv, 0.0f));
            }
        }
    }
    __syncthreads();

    // --- GEMM2: h[32x256] @ W2; 1 ntile/wave ---
    floatx4 acc2[2] = {};
    {
        const u16* aH = sA + ml * 264 + quad * 8;
        for (int kt = 0; kt < 8; ++kt) {
            short8 a0 = *(const short8*)(aH + kt * 32);
            short8 a1 = *(const short8*)(aH + 16 * 264 + kt * 32);
            short8 bfr = *(const short8*)(W2p + (size_t)((wave * 8 + kt) * 64 + lane) * 8);
            acc2[0] = __builtin_amdgcn_mfma_f32_16x16x32_bf16(a0, bfr, acc2[0], 0, 0, 0);
            acc2[1] = __builtin_amdgcn_mfma_f32_16x16x32_bf16(a1, bfr, acc2[1], 0, 0, 0);
        }
    }

    // --- epilogue: fragments -> sOut (f32) -> coalesced contiguous stores ---
    {
        const int n = wave * 16 + ml;
        const float bv = b2[n];
#pragma unroll
        for (int mt = 0; mt < 2; ++mt) {
#pragma unroll
            for (int r = 0; r < 4; ++r) {
                const int m = mt * 16 + quad * 4 + r;
                sOut[m * 256 + n] = fmaxf(acc2[mt][r] + bv, 0.0f);
            }
        }
    }
    __syncthreads();
    {
        float* dst = out + (size_t)row0 * HDIM;
#pragma unroll
        for (int k = 0; k < 2; ++k) {
            const int e = t + 1024 * k;
            *(float4*)(dst + e * 4) = *(const float4*)(sOut + e * 4);
        }
    }

    // --- tail: 128 flat elems per block ---
    if (t < 128) {
        const int e = blockIdx.x * 128 + t;
        const size_t base = (size_t)NSKIP * HDIM;
        if (e < NSKIP * 3) out[base + e] = pos_skip[e];
        else               out[base + e] = (float)batch_skip[e - NSKIP * 3];
    }
}

extern "C" void kernel_launch(void* const* d_in, const int* in_sizes, int n_in,
                              void* d_out, int out_size, void* d_ws, size_t ws_size,
                              hipStream_t stream) {
    const float* x         = (const float*)d_in[0];
    const float* pos       = (const float*)d_in[1];
    const int*   batch     = (const int*)d_in[2];
    const float* x_skip    = (const float*)d_in[3];
    const float* pos_skip  = (const float*)d_in[4];
    const int*   batch_skip= (const int*)d_in[5];
    const float* W1        = (const float*)d_in[6];
    const float* b1        = (const float*)d_in[7];
    const float* W2        = (const float*)d_in[8];
    const float* b2        = (const float*)d_in[9];
    float* out = (float*)d_out;

    // ws layout:
    char* ws = (char*)d_ws;
    u16*    W1p   = (u16*)ws;                      // 196608 B
    u16*    W2p   = (u16*)(ws + 196608);           // 131072 B
    int*    range = (int*)(ws + 327680);           // 32 B
    float4* pos4  = (float4*)(ws + 327712);        // 65536 B

    prep_kernel<<<80, 256, 0, stream>>>(W1, W2, W1p, W2p, pos, pos4, batch, range);
    mega_kernel<<<NSKIP / 32, 1024, 0, stream>>>(x, x_skip, pos4, range,
                                                 W1p, b1, W2p, b2,
                                                 pos_skip, batch_skip, out);
}